// Round 1
// baseline (91.767 us; speedup 1.0000x reference)
//
#include <hip/hip_runtime.h>
#include <math.h>

// Problem constants
#define NS 64    // sentences
#define NW 64    // words per sentence
#define NE 300   // embedding dim
#define NH 50    // hidden
#define NO 5     // output classes

__device__ __forceinline__ float fast_tanh(float x) {
  x = fminf(15.f, fmaxf(-15.f, x));
  float e = __expf(2.f * x);
  return (e - 1.f) / (e + 1.f);
}
__device__ __forceinline__ float fast_sigmoid(float x) {
  return 1.f / (1.f + __expf(-x));
}

// K1: per-sentence. Computes reps[s][0:50] and the x-part gate preactivations
// X[dir][s][gate][j] for both scan directions.
//
// Algebra: conv_k is mean-pooled over positions, so
//   mean_t conv_k(c_in)[o][t] = (1/P_k) * sum_i sum_dk w_k[o][i][dk] * A_k[i][dk]
// where A_k[i][dk] = sum over the window of words[w][i] = total[i] - edge terms.
// And total[i] = (sum_w emb_row_w) . W_word[i] + 64*b_word[i].
__global__ __launch_bounds__(256) void k_reps(
    const int* __restrict__ doc, const float* __restrict__ emb,
    const float* __restrict__ Wword, const float* __restrict__ bword,
    const float* __restrict__ w1, const float* __restrict__ b1,
    const float* __restrict__ w2, const float* __restrict__ b2,
    const float* __restrict__ w3, const float* __restrict__ b3,
    const float* __restrict__ Wfi, const float* __restrict__ bfi,
    const float* __restrict__ Wff, const float* __restrict__ bff,
    const float* __restrict__ Wfg, const float* __restrict__ bfg,
    const float* __restrict__ Wbi, const float* __restrict__ bbi,
    const float* __restrict__ Wbf, const float* __restrict__ bbf,
    const float* __restrict__ Wbg, const float* __restrict__ bbg,
    float* __restrict__ reps, float* __restrict__ Xg)
{
  __shared__ int   idxs[NW];
  __shared__ float sv[5][NE];     // 0: sum over all words; 1..4: rows w=0,1,62,63
  __shared__ float dots[5][NH];   // dot(sv[f], W_word[i])
  __shared__ float reps_s[NH];

  const int s = blockIdx.x, tid = threadIdx.x;
  if (tid < NW) idxs[tid] = doc[s * NW + tid];
  __syncthreads();

  // Phase B: column sums of gathered embedding rows (coalesced over e).
  for (int e = tid; e < NE; e += 256) {
    float acc = 0.f;
    for (int w = 0; w < NW; ++w)
      acc += emb[(size_t)idxs[w] * NE + e];
    sv[0][e] = acc;
    sv[1][e] = emb[(size_t)idxs[0]  * NE + e];
    sv[2][e] = emb[(size_t)idxs[1]  * NE + e];
    sv[3][e] = emb[(size_t)idxs[62] * NE + e];
    sv[4][e] = emb[(size_t)idxs[63] * NE + e];
  }
  __syncthreads();

  // Phase C: 5 families x 50 outputs, each a 300-dot against W_word rows.
  if (tid < 5 * NH) {
    const int fam = tid / NH, i = tid % NH;
    const float* v  = sv[fam];
    const float* wr = Wword + (size_t)i * NE;
    float acc = 0.f;
    for (int e = 0; e < NE; ++e) acc += v[e] * wr[e];
    dots[fam][i] = acc;
  }
  __syncthreads();

  // Phase D: conv means + tanh + average -> reps[s][o]
  if (tid < NH) {
    const int o = tid;
    float m1 = 0.f, m2 = 0.f, m3 = 0.f;
    for (int i = 0; i < NH; ++i) {
      const float bw    = bword[i];
      const float total = dots[0][i] + 64.f * bw;
      const float e0  = dots[1][i] + bw;
      const float e1  = dots[2][i] + bw;
      const float e62 = dots[3][i] + bw;
      const float e63 = dots[4][i] + bw;
      m1 += w1[o * NH + i] * total;
      m2 += w2[(o * NH + i) * 2 + 0] * (total - e63)
          + w2[(o * NH + i) * 2 + 1] * (total - e0);
      m3 += w3[(o * NH + i) * 3 + 0] * (total - e62 - e63)
          + w3[(o * NH + i) * 3 + 1] * (total - e0 - e63)
          + w3[(o * NH + i) * 3 + 2] * (total - e0 - e1);
    }
    m1 = b1[o] + m1 * (1.f / 64.f);
    m2 = b2[o] + m2 * (1.f / 63.f);
    m3 = b3[o] + m3 * (1.f / 62.f);
    const float r = (fast_tanh(m1) + fast_tanh(m2) + fast_tanh(m3)) * (1.f / 3.f);
    reps_s[o] = r;
    reps[s * NH + o] = r;
  }
  __syncthreads();

  // Phase E: x-part gate preactivations for both directions.
  // X[((dir*64 + s)*3 + gate)*50 + j] = b[j] + W[gate][j][0:50] . reps_s
  for (int task = tid; task < 6 * NH; task += 256) {
    const int dg = task / NH, j = task % NH;
    const float* Wp; const float* bp;
    switch (dg) {
      case 0: Wp = Wfi; bp = bfi; break;
      case 1: Wp = Wff; bp = bff; break;
      case 2: Wp = Wfg; bp = bfg; break;
      case 3: Wp = Wbi; bp = bbi; break;
      case 4: Wp = Wbf; bp = bbf; break;
      default: Wp = Wbg; bp = bbg; break;
    }
    float acc = bp[j];
    for (int k = 0; k < NH; ++k) acc += Wp[j * 100 + k] * reps_s[k];
    const int dir = dg / 3, gate = dg % 3;
    Xg[((dir * NS + s) * 3 + gate) * NH + j] = acc;
  }
}

// K2: the two sequential scans (wave 0 = forward, wave 1 = backward) + the
// fused mean/output-matvec/softmax epilogue. h lives lane-resident; the h-part
// weights (3 x 50) live in registers; cross-lane h broadcast via __shfl.
__global__ __launch_bounds__(128, 1) void k_scan(
    const float* __restrict__ Xg,
    const float* __restrict__ Wfi, const float* __restrict__ Wff, const float* __restrict__ Wfg,
    const float* __restrict__ Wbi, const float* __restrict__ Wbf, const float* __restrict__ Wbg,
    const float* __restrict__ Wout, const float* __restrict__ bout,
    float* __restrict__ out)
{
  __shared__ float gsum[2 * NH];
  __shared__ float logits[NO];

  const int tid = threadIdx.x;
  const int wave = tid >> 6, lane = tid & 63;
  const int j = (lane < NH) ? lane : 0;   // lanes 50..63 shadow lane 0 (results unused)

  const float* Wi = wave ? Wbi : Wfi;
  const float* Wf = wave ? Wbf : Wff;
  const float* Wg = wave ? Wbg : Wfg;

  float wih[NH], wfh[NH], wgh[NH];
#pragma unroll
  for (int k = 0; k < NH; ++k) {
    wih[k] = Wi[j * 100 + 50 + k];
    wfh[k] = Wf[j * 100 + 50 + k];
    wgh[k] = Wg[j * 100 + 50 + k];
  }

  // software-prefetched X reads (L2-hot: K1 just wrote them)
  const int t0 = wave ? (NS - 1) : 0;
  int b0 = (wave * NS + t0) * 3 * NH;
  float nai = Xg[b0 + j], naf = Xg[b0 + 50 + j], nag = Xg[b0 + 100 + j];

  float h = 0.f, hs = 0.f;
  for (int n = 0; n < NS; ++n) {
    float ai = nai, af = naf, ag = nag;
    if (n < NS - 1) {
      const int t = wave ? (NS - 2 - n) : (n + 1);
      const int bb = (wave * NS + t) * 3 * NH;
      nai = Xg[bb + j]; naf = Xg[bb + 50 + j]; nag = Xg[bb + 100 + j];
    }
#pragma unroll
    for (int k = 0; k < NH; ++k) {
      const float hv = __shfl(h, k);
      ai += wih[k] * hv;
      af += wfh[k] * hv;
      ag += wgh[k] * hv;
    }
    const float it = fast_sigmoid(ai);
    const float ft = fast_sigmoid(af);
    const float gt = fast_tanh(ag);
    h = fast_tanh(it * gt + ft * h);
    hs += h;
  }
  if (lane < NH) gsum[wave * NH + lane] = hs * (1.f / 64.f);
  __syncthreads();

  if (tid < NO) {
    float acc = bout[tid];
    for (int k = 0; k < 2 * NH; ++k) acc += Wout[tid * 2 * NH + k] * gsum[k];
    logits[tid] = acc;
  }
  __syncthreads();

  if (tid == 0) {
    float m = logits[0];
    for (int i = 1; i < NO; ++i) m = fmaxf(m, logits[i]);
    float ex[NO], se = 0.f;
    for (int i = 0; i < NO; ++i) { ex[i] = __expf(logits[i] - m); se += ex[i]; }
    for (int i = 0; i < NO; ++i) out[i] = ex[i] / se;
  }
}

extern "C" void kernel_launch(void* const* d_in, const int* in_sizes, int n_in,
                              void* d_out, int out_size, void* d_ws, size_t ws_size,
                              hipStream_t stream) {
  const int*   doc   = (const int*)  d_in[0];
  const float* emb   = (const float*)d_in[1];
  const float* Wword = (const float*)d_in[2];
  const float* bword = (const float*)d_in[3];
  const float* w1    = (const float*)d_in[4];
  const float* b1    = (const float*)d_in[5];
  const float* w2    = (const float*)d_in[6];
  const float* b2    = (const float*)d_in[7];
  const float* w3    = (const float*)d_in[8];
  const float* b3    = (const float*)d_in[9];
  const float* Wfi   = (const float*)d_in[10];
  const float* bfi   = (const float*)d_in[11];
  const float* Wff   = (const float*)d_in[12];
  const float* bff   = (const float*)d_in[13];
  const float* Wfg   = (const float*)d_in[14];
  const float* bfg   = (const float*)d_in[15];
  const float* Wbi   = (const float*)d_in[16];
  const float* bbi   = (const float*)d_in[17];
  const float* Wbf   = (const float*)d_in[18];
  const float* bbf   = (const float*)d_in[19];
  const float* Wbg   = (const float*)d_in[20];
  const float* bbg   = (const float*)d_in[21];
  const float* Wout  = (const float*)d_in[22];
  const float* bout  = (const float*)d_in[23];

  float* reps = (float*)d_ws;            // 64*50 floats
  float* Xg   = reps + NS * NH;          // 2*64*3*50 floats
  float* outp = (float*)d_out;

  k_reps<<<dim3(NS), dim3(256), 0, stream>>>(
      doc, emb, Wword, bword, w1, b1, w2, b2, w3, b3,
      Wfi, bfi, Wff, bff, Wfg, bfg, Wbi, bbi, Wbf, bbf, Wbg, bbg,
      reps, Xg);

  k_scan<<<dim3(1), dim3(128), 0, stream>>>(
      Xg, Wfi, Wff, Wfg, Wbi, Wbf, Wbg, Wout, bout, outp);
}

// Round 2
// 63.182 us; speedup vs baseline: 1.4524x; 1.4524x over previous
//
#include <hip/hip_runtime.h>
#include <math.h>

// Problem constants
#define NS 64    // sentences
#define NW 64    // words per sentence
#define NE 300   // embedding dim
#define NH 50    // hidden
#define NO 5     // output classes

__device__ __forceinline__ float fast_tanh(float x) {
  x = fminf(15.f, fmaxf(-15.f, x));
  float e = __expf(2.f * x);
  return (e - 1.f) / (e + 1.f);
}
__device__ __forceinline__ float fast_sigmoid(float x) {
  return 1.f / (1.f + __expf(-x));
}

// ---------------------------------------------------------------------------
// K1: per-sentence. Computes reps[s][0:50] and the x-part gate preactivations
// X[dir][s][gate][j] for both scan directions.
//
// Algebra: conv_k is mean-pooled over positions, so only the window SUMS of
// words[w][i] are needed; windows are total - edge terms, and the word
// projection distributes over the word-sum:
//   sum_w (emb_row_w . W_word[i]) = (sum_w emb_row_w) . W_word[i]
// ---------------------------------------------------------------------------
__global__ __launch_bounds__(512) void k_reps(
    const int* __restrict__ doc, const float* __restrict__ emb,
    const float* __restrict__ Wword, const float* __restrict__ bword,
    const float* __restrict__ w1, const float* __restrict__ b1,
    const float* __restrict__ w2, const float* __restrict__ b2,
    const float* __restrict__ w3, const float* __restrict__ b3,
    const float* __restrict__ Wfi, const float* __restrict__ bfi,
    const float* __restrict__ Wff, const float* __restrict__ bff,
    const float* __restrict__ Wfg, const float* __restrict__ bfg,
    const float* __restrict__ Wbi, const float* __restrict__ bbi,
    const float* __restrict__ Wbf, const float* __restrict__ bbf,
    const float* __restrict__ Wbg, const float* __restrict__ bbg,
    float* __restrict__ reps, float* __restrict__ Xg)
{
  __shared__ int   idxs[NW];
  __shared__ float sv[5][304];    // 0: sum over all words; 1..4: rows 0,1,62,63
  __shared__ float ph1[304];      // group-1 partial of the w-sum
  __shared__ float dots[5][NH];
  __shared__ float reps_s[NH];

  const int s = blockIdx.x, tid = threadIdx.x;
  if (tid < NW) idxs[tid] = doc[s * NW + tid];
  __syncthreads();

  // Phase B: column sums of the 64 gathered rows, split across 2 thread
  // groups (serial load depth 32 each), coalesced over e.
  const int p = tid >> 8, et = tid & 255;
  for (int e = et; e < NE; e += 256) {
    float acc = 0.f;
    const int w0 = p * 32;
#pragma unroll 8
    for (int w = w0; w < w0 + 32; ++w)
      acc += emb[(size_t)idxs[w] * NE + e];
    if (p == 0) sv[0][e] = acc; else ph1[e] = acc;
    if (p == 0) {
      sv[1][e] = emb[(size_t)idxs[0]  * NE + e];
      sv[2][e] = emb[(size_t)idxs[1]  * NE + e];
    } else {
      sv[3][e] = emb[(size_t)idxs[62] * NE + e];
      sv[4][e] = emb[(size_t)idxs[63] * NE + e];
    }
  }
  __syncthreads();
  if (tid < NE) sv[0][tid] += ph1[tid];
  __syncthreads();

  // Phase C: 5 families x 50 outputs, each a 300-dot against W_word rows.
  if (tid < 5 * NH) {
    const int fam = tid / NH, i = tid % NH;
    const float4* v4 = (const float4*)&sv[fam][0];
    const float4* w4 = (const float4*)(Wword + (size_t)i * NE);
    float a0 = 0.f, a1 = 0.f;
#pragma unroll
    for (int c = 0; c < NE / 4; ++c) {
      const float4 v = v4[c], w = w4[c];
      a0 += v.x * w.x + v.y * w.y;
      a1 += v.z * w.z + v.w * w.w;
    }
    dots[fam][i] = a0 + a1;
  }
  __syncthreads();

  // Phase D: conv means + tanh + average -> reps[s][o]
  if (tid < NH) {
    const int o = tid;
    float m1 = 0.f, m2 = 0.f, m3 = 0.f;
    for (int i = 0; i < NH; ++i) {
      const float bw    = bword[i];
      const float total = dots[0][i] + 64.f * bw;
      const float e0  = dots[1][i] + bw;
      const float e1  = dots[2][i] + bw;
      const float e62 = dots[3][i] + bw;
      const float e63 = dots[4][i] + bw;
      m1 += w1[o * NH + i] * total;
      m2 += w2[(o * NH + i) * 2 + 0] * (total - e63)
          + w2[(o * NH + i) * 2 + 1] * (total - e0);
      m3 += w3[(o * NH + i) * 3 + 0] * (total - e62 - e63)
          + w3[(o * NH + i) * 3 + 1] * (total - e0 - e63)
          + w3[(o * NH + i) * 3 + 2] * (total - e0 - e1);
    }
    m1 = b1[o] + m1 * (1.f / 64.f);
    m2 = b2[o] + m2 * (1.f / 63.f);
    m3 = b3[o] + m3 * (1.f / 62.f);
    const float r = (fast_tanh(m1) + fast_tanh(m2) + fast_tanh(m3)) * (1.f / 3.f);
    reps_s[o] = r;
    reps[s * NH + o] = r;
  }
  __syncthreads();

  // Phase E: x-part gate preactivations for both directions.
  if (tid < 6 * NH) {
    const int dg = tid / NH, j = tid % NH;
    const float* Wp; const float* bp;
    switch (dg) {
      case 0: Wp = Wfi; bp = bfi; break;
      case 1: Wp = Wff; bp = bff; break;
      case 2: Wp = Wfg; bp = bfg; break;
      case 3: Wp = Wbi; bp = bbi; break;
      case 4: Wp = Wbf; bp = bbf; break;
      default: Wp = Wbg; bp = bbg; break;
    }
    float acc = bp[j];
    for (int k = 0; k < NH; ++k) acc += Wp[j * 100 + k] * reps_s[k];
    const int dir = dg / 3, gate = dg % 3;
    Xg[((dir * NS + s) * 3 + gate) * NH + j] = acc;
  }
}

// ---------------------------------------------------------------------------
// K2: the two sequential scans + fused epilogue. 6 waves: wave = (dir, gate).
// Each lane holds only its gate's 50 h-weights (low pressure, no spill).
// h is exchanged through LDS; the h broadcast is 13 float4 uniform-address
// reads (hardware broadcast, conflict-free) instead of 50 serialized shuffles.
// ---------------------------------------------------------------------------
__global__ __launch_bounds__(384, 1) void k_scan(
    const float* __restrict__ Xg,
    const float* __restrict__ Wfi, const float* __restrict__ Wff, const float* __restrict__ Wfg,
    const float* __restrict__ Wbi, const float* __restrict__ Wbf, const float* __restrict__ Wbg,
    const float* __restrict__ Wout, const float* __restrict__ bout,
    float* __restrict__ out)
{
  __shared__ float h_sh[2][56];       // padded to 56 so float4 reads cover 52
  __shared__ float gate_sh[2][3][64];
  __shared__ float gsum[2 * NH];
  __shared__ float logits[NO];

  const int tid  = threadIdx.x;
  const int wid  = tid >> 6, lane = tid & 63;
  const int d    = wid / 3, g = wid % 3;      // direction, gate
  const int j    = (lane < NH) ? lane : 0;    // lanes 50..63 shadow lane 0

  const float* Wp;
  if (d == 0) Wp = (g == 0) ? Wfi : (g == 1) ? Wff : Wfg;
  else        Wp = (g == 0) ? Wbi : (g == 1) ? Wbf : Wbg;

  // 50 h-weights per lane (+2 zero pad so the dot runs in float4 chunks of h)
  float wk[52];
#pragma unroll
  for (int k = 0; k < NH; ++k) wk[k] = Wp[j * 100 + 50 + k];
  wk[50] = 0.f; wk[51] = 0.f;

  // init shared h to zero
  if (tid < 2 * 56) ((float*)h_sh)[tid] = 0.f;
  __syncthreads();

  // rolling X prefetch: X[((d*64 + t)*3 + g)*50 + j]
  const int t0 = d ? (NS - 1) : 0;
  float xa = Xg[((d * NS + t0) * 3 + g) * NH + j];

  float hj = 0.f, hs = 0.f;
  for (int n = 0; n < NS; ++n) {
    float a = xa;
    if (n < NS - 1) {
      const int t = d ? (NS - 2 - n) : (n + 1);
      xa = Xg[((d * NS + t) * 3 + g) * NH + j];
    }
    // a += dot(wk, h) via 13 float4 broadcast reads
    const float4* h4 = (const float4*)&h_sh[d][0];
    float acc0 = 0.f, acc1 = 0.f;
#pragma unroll
    for (int c = 0; c < 13; ++c) {
      const float4 hv = h4[c];
      acc0 += wk[4 * c + 0] * hv.x;
      acc1 += wk[4 * c + 1] * hv.y;
      acc0 += wk[4 * c + 2] * hv.z;
      acc1 += wk[4 * c + 3] * hv.w;
    }
    a += acc0 + acc1;

    const float act = (g == 2) ? fast_tanh(a) : fast_sigmoid(a);
    if (lane < NH) gate_sh[d][g][lane] = act;
    __syncthreads();   // gates visible; everyone done reading h_sh

    const float iv = gate_sh[d][0][j];
    const float fv = gate_sh[d][1][j];
    const float gv = gate_sh[d][2][j];
    hj = fast_tanh(iv * gv + fv * hj);   // redundant across the 3 gate-waves
    hs += hj;
    if (g == 0 && lane < NH) h_sh[d][lane] = hj;
    __syncthreads();   // new h visible for next step
  }

  if (g == 0 && lane < NH) gsum[d * NH + lane] = hs * (1.f / 64.f);
  __syncthreads();

  if (tid < NO) {
    float acc = bout[tid];
    for (int k = 0; k < 2 * NH; ++k) acc += Wout[tid * 2 * NH + k] * gsum[k];
    logits[tid] = acc;
  }
  __syncthreads();

  if (tid == 0) {
    float m = logits[0];
    for (int i = 1; i < NO; ++i) m = fmaxf(m, logits[i]);
    float ex[NO], se = 0.f;
    for (int i = 0; i < NO; ++i) { ex[i] = __expf(logits[i] - m); se += ex[i]; }
    for (int i = 0; i < NO; ++i) out[i] = ex[i] / se;
  }
}

extern "C" void kernel_launch(void* const* d_in, const int* in_sizes, int n_in,
                              void* d_out, int out_size, void* d_ws, size_t ws_size,
                              hipStream_t stream) {
  const int*   doc   = (const int*)  d_in[0];
  const float* emb   = (const float*)d_in[1];
  const float* Wword = (const float*)d_in[2];
  const float* bword = (const float*)d_in[3];
  const float* w1    = (const float*)d_in[4];
  const float* b1    = (const float*)d_in[5];
  const float* w2    = (const float*)d_in[6];
  const float* b2    = (const float*)d_in[7];
  const float* w3    = (const float*)d_in[8];
  const float* b3    = (const float*)d_in[9];
  const float* Wfi   = (const float*)d_in[10];
  const float* bfi   = (const float*)d_in[11];
  const float* Wff   = (const float*)d_in[12];
  const float* bff   = (const float*)d_in[13];
  const float* Wfg   = (const float*)d_in[14];
  const float* bfg   = (const float*)d_in[15];
  const float* Wbi   = (const float*)d_in[16];
  const float* bbi   = (const float*)d_in[17];
  const float* Wbf   = (const float*)d_in[18];
  const float* bbf   = (const float*)d_in[19];
  const float* Wbg   = (const float*)d_in[20];
  const float* bbg   = (const float*)d_in[21];
  const float* Wout  = (const float*)d_in[22];
  const float* bout  = (const float*)d_in[23];

  float* reps = (float*)d_ws;            // 64*50 floats
  float* Xg   = reps + NS * NH;          // 2*64*3*50 floats
  float* outp = (float*)d_out;

  k_reps<<<dim3(NS), dim3(512), 0, stream>>>(
      doc, emb, Wword, bword, w1, b1, w2, b2, w3, b3,
      Wfi, bfi, Wff, bff, Wfg, bfg, Wbi, bbi, Wbf, bbf, Wbg, bbg,
      reps, Xg);

  k_scan<<<dim3(1), dim3(384), 0, stream>>>(
      Xg, Wfi, Wff, Wfg, Wbi, Wbf, Wbg, Wout, bout, outp);
}